// Round 9
// baseline (286.100 us; speedup 1.0000x reference)
//
#include <hip/hip_runtime.h>
#include <hip/hip_fp16.h>

#define DIM 128
#define NPB 256        // nodes per bucket
#define BCAP 5120      // bucket capacity (mean 4092, +16 sigma)
#define T_SCAT 4096

typedef _Float16 half8 __attribute__((ext_vector_type(8)));
typedef float floatx4 __attribute__((ext_vector_type(4)));
typedef float floatx2 __attribute__((ext_vector_type(2)));

// ---------------- shared gemm block body: 64 nodes -> A fp8 ----------------
__device__ __forceinline__ void gemm_block(const float* __restrict__ X,
                                           const __half* __restrict__ w1frag,
                                           unsigned char* __restrict__ A,
                                           int N, int gb) {
    const int t = threadIdx.x;
    const int w = t >> 6, l = t & 63;
    const int q = l >> 4;
    const int node = gb * 64 + w * 16 + (l & 15);
    const bool valid = node < N;
    half8 bfrag[4];
#pragma unroll
    for (int ks = 0; ks < 4; ks++) {
        float4 f0 = make_float4(0, 0, 0, 0), f1 = make_float4(0, 0, 0, 0);
        if (valid) {
            const float* px = X + (size_t)node * DIM + ks * 32 + q * 8;
            f0 = *(const float4*)px;
            f1 = *(const float4*)(px + 4);
        }
        bfrag[ks][0] = (_Float16)f0.x; bfrag[ks][1] = (_Float16)f0.y;
        bfrag[ks][2] = (_Float16)f0.z; bfrag[ks][3] = (_Float16)f0.w;
        bfrag[ks][4] = (_Float16)f1.x; bfrag[ks][5] = (_Float16)f1.y;
        bfrag[ks][6] = (_Float16)f1.z; bfrag[ks][7] = (_Float16)f1.w;
    }
    const half8* wf = (const half8*)w1frag;
#pragma unroll
    for (int ct = 0; ct < 8; ct++) {
        floatx4 acc = {0.f, 0.f, 0.f, 0.f};
#pragma unroll
        for (int ks = 0; ks < 4; ks++) {
            half8 afrag = wf[(ct * 4 + ks) * 64 + l];
            acc = __builtin_amdgcn_mfma_f32_16x16x32_f16(afrag, bfrag[ks], acc, 0, 0, 0);
        }
        if (valid) {
            int st = 0;
            st = __builtin_amdgcn_cvt_pk_fp8_f32(acc[0], acc[1], st, false);
            st = __builtin_amdgcn_cvt_pk_fp8_f32(acc[2], acc[3], st, true);
            *(int*)(A + (size_t)node * DIM + ct * 16 + q * 4) = st;
        }
    }
}

// ---------------- L1 prep: w1frag, w2o, cbuf, zero bcur ----------------
__global__ void prep_k(const float* __restrict__ W1, const float* __restrict__ W2,
                       const float* __restrict__ Wo, const float* __restrict__ b2,
                       const float* __restrict__ bo,
                       __half* __restrict__ w1frag, float* __restrict__ w2o,
                       float* __restrict__ cbuf, int* __restrict__ bcur) {
    if (blockIdx.x < 8) {
        int idx = blockIdx.x * 256 + threadIdx.x;   // 0..2047
        int ct = idx >> 8, ks = (idx >> 6) & 3, l = idx & 63;
        int m = l & 15, q = l >> 4;
        half8 vals;
#pragma unroll
        for (int j = 0; j < 8; j++)
            vals[j] = (_Float16)W1[(ks * 32 + q * 8 + j) * DIM + ct * 16 + m];
        ((half8*)w1frag)[idx] = vals;
    } else if (blockIdx.x == 8) {
        int t = threadIdx.x;
        if (t < 128) {
            float s = 0.f;
            for (int k = 0; k < 128; k++) s += W2[t * 128 + k] * Wo[k];
            w2o[t] = s;
        }
        if (t == 0) {
            float c = bo[0];
            for (int k = 0; k < 128; k++) c += b2[k] * Wo[k];
            cbuf[0] = c;
        }
    } else {
#pragma unroll
        for (int i = 0; i < 4; i++) bcur[threadIdx.x + i * 256] = 0;
    }
}

// ---------------- L2: bscatter (two-pass) + global degree count + ALL gemm ----------
// bucket b = dst >> 8; bucket b owns [b*BCAP, (b+1)*BCAP) in be and csr.
__global__ __launch_bounds__(256) void scatter_gemm_k(
        const int* __restrict__ ei, int E, int ntiles,
        int2* __restrict__ be, int* __restrict__ bcur, int* __restrict__ deg,
        const float* __restrict__ X, const __half* __restrict__ w1frag,
        unsigned char* __restrict__ A, int N) {
    if (blockIdx.x >= (unsigned)ntiles) {
        gemm_block(X, w1frag, A, N, blockIdx.x - ntiles);
        return;
    }
    __shared__ int lcnt[1024];
    __shared__ int lscan[1024];
    __shared__ int lbase[1024];
    __shared__ int wsum[4];
    __shared__ int2 stage[T_SCAT];
    const int t = threadIdx.x;
    const int lane = t & 63, w = t >> 6;
    const int tile0 = blockIdx.x * T_SCAT;
    int tcnt = E - tile0; if (tcnt > T_SCAT) tcnt = T_SCAT;
    for (int i = t; i < 1024; i += 256) lcnt[i] = 0;
    __syncthreads();
    // pass A: bucket histogram + global per-node degree (fire-and-forget)
    for (int i = t; i < tcnt; i += 256) {
        int d = ei[E + tile0 + i];
        atomicAdd(&lcnt[d >> 8], 1);
        atomicAdd(&deg[d], 1);
    }
    __syncthreads();
    // scan 1024 counts (4/thread, shfl wave-scan); reserve global bucket space
    const int b4 = t * 4;
    int c0 = lcnt[b4], c1 = lcnt[b4 + 1], c2 = lcnt[b4 + 2], c3 = lcnt[b4 + 3];
    int s4 = c0 + c1 + c2 + c3;
    int v = s4;
#pragma unroll
    for (int off = 1; off < 64; off <<= 1) {
        int u = __shfl_up(v, off, 64);
        if (lane >= off) v += u;
    }
    if (lane == 63) wsum[w] = v;
    __syncthreads();
    int wbase = 0;
#pragma unroll
    for (int i = 0; i < 4; i++) wbase += (i < w) ? wsum[i] : 0;
    int run = wbase + v - s4;
    lscan[b4] = run;
    if (c0) lbase[b4] = b4 * BCAP + atomicAdd(&bcur[b4], c0);
    run += c0; lscan[b4 + 1] = run;
    if (c1) lbase[b4 + 1] = (b4 + 1) * BCAP + atomicAdd(&bcur[b4 + 1], c1);
    run += c1; lscan[b4 + 2] = run;
    if (c2) lbase[b4 + 2] = (b4 + 2) * BCAP + atomicAdd(&bcur[b4 + 2], c2);
    run += c2; lscan[b4 + 3] = run;
    if (c3) lbase[b4 + 3] = (b4 + 3) * BCAP + atomicAdd(&bcur[b4 + 3], c3);
    lcnt[b4] = 0; lcnt[b4 + 1] = 0; lcnt[b4 + 2] = 0; lcnt[b4 + 3] = 0;
    __syncthreads();
    // pass B: re-read (L2-hot), rank, stage
    for (int i = t; i < tcnt; i += 256) {
        int s = ei[tile0 + i];
        int d = ei[E + tile0 + i];
        int b = d >> 8;
        int r = atomicAdd(&lcnt[b], 1);
        stage[lscan[b] + r] = make_int2(s, d);
    }
    __syncthreads();
    // contiguous-run copy out (~10.5-edge runs)
    for (int i = t; i < tcnt; i += 256) {
        int2 ed = stage[i];
        int b = ed.y >> 8;
        be[lbase[b] + (i - lscan[b])] = ed;
    }
}

__device__ __forceinline__ void dec8(int2 r, float* f) {
    floatx2 a = __builtin_amdgcn_cvt_pk_f32_fp8(r.x, false);
    floatx2 b = __builtin_amdgcn_cvt_pk_f32_fp8(r.x, true);
    floatx2 c = __builtin_amdgcn_cvt_pk_f32_fp8(r.y, false);
    floatx2 d = __builtin_amdgcn_cvt_pk_f32_fp8(r.y, true);
    f[0] = a[0]; f[1] = a[1]; f[2] = b[0]; f[3] = b[1];
    f[4] = c[0]; f[5] = c[1]; f[6] = d[0]; f[7] = d[1];
}

// ---------------- L3: fused bucket sort + layer-1 aggregation ----------------
// 1024 threads/block, one 256-node bucket per block.
// Sort bucket into LDS stage (sorted srcs); write csr/rp/re/dinv for final_k;
// then 32 groups of 32 lanes aggregate the bucket's nodes from LDS src lists.
// Remote dinv comes from rsqrtf(deg[s]+1) — deg completed in L2.
__global__ __launch_bounds__(1024) void sort_agg_k(
        const int2* __restrict__ be, const int* __restrict__ bcur,
        const int* __restrict__ deg,
        int* __restrict__ csr, int* __restrict__ rp, int* __restrict__ re,
        float* __restrict__ dinv,
        const unsigned char* __restrict__ A,
        const float* __restrict__ b1, const float* __restrict__ w2o,
        float* __restrict__ z, int N) {
    __shared__ int lcnt[256];
    __shared__ int lscan[256];
    __shared__ int lc2[256];
    __shared__ int wsum[4];
    __shared__ int stage[BCAP];
    const int t = threadIdx.x;
    const int b = blockIdx.x;
    const int s = b * BCAP;
    int cnt = bcur[b]; if (cnt > BCAP) cnt = BCAP;
    if (t < 256) { lcnt[t] = 0; lc2[t] = 0; }
    __syncthreads();
    // phase 1: histogram (per-node counts within bucket)
    for (int i = t; i < cnt; i += 1024)
        atomicAdd(&lcnt[be[s + i].y & 255], 1);
    __syncthreads();
    // phase 2: scan 256 counters (threads 0..255)
    if (t < 256) {
        const int lane = t & 63, w = t >> 6;
        int v = lcnt[t];
        int iv = v;
#pragma unroll
        for (int off = 1; off < 64; off <<= 1) {
            int u = __shfl_up(iv, off, 64);
            if (lane >= off) iv += u;
        }
        if (lane == 63) wsum[w] = iv;
        __syncthreads();
        int wbase = 0;
#pragma unroll
        for (int i = 0; i < 4; i++) wbase += (i < w) ? wsum[i] : 0;
        int excl = wbase + iv - v;
        lscan[t] = excl;
        int node = b * NPB + t;
        if (node < N) {
            rp[node] = s + excl;
            re[node] = s + excl + v;
            dinv[node] = rsqrtf((float)v + 1.0f);
        }
    } else {
        __syncthreads();
    }
    __syncthreads();
    // phase 3: rank + stage sorted srcs
    for (int i = t; i < cnt; i += 1024) {
        int2 ed = be[s + i];
        int d = ed.y & 255;
        int r = atomicAdd(&lc2[d], 1);
        stage[lscan[d] + r] = ed.x;
    }
    __syncthreads();
    // phase 4: csr write-out (needed by final_k)
    for (int i = t; i < cnt; i += 1024) csr[s + i] = stage[i];
    // phase 5: aggregation — 32 groups x 32 lanes, 8 nodes per group
    const int li = t & 31;
    const int grp = t >> 5;
    const int eoff = (li & 15) * 8;
    for (int nn = grp; nn < NPB; nn += 32) {
        int node = b * NPB + nn;
        if (node >= N) continue;
        const int cn = lcnt[nn];
        const int s0 = lscan[nn];
        const float dn = rsqrtf((float)cn + 1.0f);
        float acc[8];
        {
            int2 raw = *(const int2*)(A + (size_t)node * DIM + eoff);
            float hv[8]; dec8(raw, hv);
            float w0 = (li < 16) ? dn * dn : 0.f;
#pragma unroll
            for (int e = 0; e < 8; e++) acc[e] = hv[e] * w0;
        }
        for (int base = 0; base < cn; base += 32) {
            int sidx = 0; float dsl = 0.f;
            if (base + li < cn) {
                sidx = stage[s0 + base + li];
                dsl = rsqrtf((float)deg[sidx] + 1.0f);
            }
            int nloc = cn - base; if (nloc > 32) nloc = 32;
            int npair = (nloc + 1) >> 1;
#pragma unroll 2
            for (int j = 0; j < npair; j++) {
                int sel = 2 * j + (li >> 4);
                int ssrc = __shfl(sidx, sel, 32);
                float wgt = __shfl(dsl, sel, 32) * dn;
                int2 hraw = *(const int2*)(A + (size_t)ssrc * DIM + eoff);
                float h[8]; dec8(hraw, h);
#pragma unroll
                for (int e = 0; e < 8; e++) acc[e] = fmaf(h[e], wgt, acc[e]);
            }
        }
#pragma unroll
        for (int e = 0; e < 8; e++) acc[e] += __shfl_xor(acc[e], 16, 32);
        float sum = 0.f;
        if (li < 16) {
            float4 b0 = *(const float4*)(b1 + eoff);
            float4 b3 = *(const float4*)(b1 + eoff + 4);
            float4 w0 = *(const float4*)(w2o + eoff);
            float4 w3 = *(const float4*)(w2o + eoff + 4);
            sum  = fmaxf(acc[0] + b0.x, 0.f) * w0.x;
            sum += fmaxf(acc[1] + b0.y, 0.f) * w0.y;
            sum += fmaxf(acc[2] + b0.z, 0.f) * w0.z;
            sum += fmaxf(acc[3] + b0.w, 0.f) * w0.w;
            sum += fmaxf(acc[4] + b3.x, 0.f) * w3.x;
            sum += fmaxf(acc[5] + b3.y, 0.f) * w3.y;
            sum += fmaxf(acc[6] + b3.z, 0.f) * w3.z;
            sum += fmaxf(acc[7] + b3.w, 0.f) * w3.w;
        }
#pragma unroll
        for (int off = 16; off > 0; off >>= 1) sum += __shfl_down(sum, off, 32);
        if (li == 0) z[node] = sum;
    }
}

// ---------------- final: out[n] = dn*sum(dinv[s]*z[s]) + dn^2*z[n] + c ----------------
__global__ void final_k(const float* __restrict__ z, const float* __restrict__ dinv,
                        const int* __restrict__ rp, const int* __restrict__ re,
                        const int* __restrict__ csr_src,
                        const float* __restrict__ cbuf, float* __restrict__ out, int N) {
    int n = blockIdx.x * 256 + threadIdx.x;
    if (n >= N) return;
    float dn = dinv[n];
    int s0 = rp[n], s1 = re[n];
    float s = 0.f;
    for (int i = s0; i < s1; i++) {
        int sx = csr_src[i];
        s = fmaf(dinv[sx], z[sx], s);
    }
    out[n] = fmaf(dn, s, fmaf(dn * dn, z[n], cbuf[0]));
}

extern "C" void kernel_launch(void* const* d_in, const int* in_sizes, int n_in,
                              void* d_out, int out_size, void* d_ws, size_t ws_size,
                              hipStream_t stream) {
    const float* x  = (const float*)d_in[0];
    const int*   ei = (const int*)d_in[1];
    const float* W1 = (const float*)d_in[2];
    const float* b1 = (const float*)d_in[3];
    const float* W2 = (const float*)d_in[4];
    const float* b2 = (const float*)d_in[5];
    const float* Wo = (const float*)d_in[6];
    const float* bo = (const float*)d_in[7];
    float* out = (float*)d_out;

    const int N = in_sizes[0] / DIM;
    const int E = in_sizes[1] / 2;
    const int NB = (N + NPB - 1) >> 8;         // 256-node buckets
    const int ntiles = (E + T_SCAT - 1) / T_SCAT;
    const int ngemm = (N + 63) / 64;

    char* p = (char*)d_ws;
    auto alloc = [&](size_t bytes) {
        void* r = (void*)p;
        p += (bytes + 255) & ~size_t(255);
        return r;
    };
    unsigned char* A = (unsigned char*)alloc((size_t)N * DIM);          // 12.8 MB
    int2*  be     = (int2*)alloc((size_t)NB * BCAP * 8);                // 16 MB
    int*   csr    = (int*)alloc((size_t)NB * BCAP * 4);                 // 8 MB
    int*   deg    = (int*)alloc((size_t)N * 4);
    float* z      = (float*)alloc((size_t)N * 4);
    float* dinv   = (float*)alloc((size_t)N * 4);
    float* w2o    = (float*)alloc(128 * 4);
    float* cbuf   = (float*)alloc(16);
    __half* w1frag= (__half*)alloc(2048 * 8 * 2);   // 32 KB
    int* rp       = (int*)alloc((size_t)N * 4);
    int* re       = (int*)alloc((size_t)N * 4);
    int* bcur     = (int*)alloc(1024 * 4);

    hipMemsetAsync(deg, 0, (size_t)N * 4, stream);
    prep_k<<<10, 256, 0, stream>>>(W1, W2, Wo, b2, bo, w1frag, w2o, cbuf, bcur);
    scatter_gemm_k<<<ntiles + ngemm, 256, 0, stream>>>(ei, E, ntiles, be, bcur, deg,
                                                       x, w1frag, A, N);
    sort_agg_k<<<NB, 1024, 0, stream>>>(be, bcur, deg, csr, rp, re, dinv,
                                        A, b1, w2o, z, N);
    final_k<<<(N + 255) / 256, 256, 0, stream>>>(z, dinv, rp, re, csr, cbuf, out, N);
}